// Round 9
// baseline (167.749 us; speedup 1.0000x reference)
//
#include <hip/hip_runtime.h>

typedef unsigned short ushort_t;
typedef short short8 __attribute__((ext_vector_type(8)));
typedef float f32x4 __attribute__((ext_vector_type(4)));
typedef unsigned int u32x4 __attribute__((ext_vector_type(4)));

typedef f32x4 f32x4a __attribute__((may_alias));
typedef u32x4 u32x4a __attribute__((may_alias));
typedef short8 short8a __attribute__((may_alias));

#define BC 64
#define PRP 74   // P-buffer pitch for fallback kernel

#define BAR_LGKM() asm volatile("s_waitcnt lgkmcnt(0)\n\ts_barrier" ::: "memory")
#define BAR_VM12() asm volatile("s_waitcnt vmcnt(12)\n\ts_barrier" ::: "memory")
#define BAR_VM8()  asm volatile("s_waitcnt vmcnt(8)\n\ts_barrier" ::: "memory")
#define BAR_VM4()  asm volatile("s_waitcnt vmcnt(4)\n\ts_barrier" ::: "memory")
#define BAR_VM0()  asm volatile("s_waitcnt vmcnt(0)\n\ts_barrier" ::: "memory")

__device__ __forceinline__ ushort_t f2bf(float x) {
    unsigned u = __float_as_uint(x);
    u = (u + 0x7fffu + ((u >> 16) & 1u)) >> 16;   // RNE
    return (ushort_t)u;
}

__device__ __forceinline__ void dma16(const void* g, void* lds) {
    __builtin_amdgcn_global_load_lds(
        (const __attribute__((address_space(1))) unsigned int*)g,
        (__attribute__((address_space(3))) unsigned int*)lds, 16, 0, 0);
}

// ---------- fused pre-pass: K -> bf16 (same layout), V -> bf16 transposed ----------
// Vt is TILE-MAJOR: [b][jtile][d(64)][j(64)]. Also zeroes the work counter.
__global__ __launch_bounds__(256) void prep_kv(
    const float* __restrict__ K, const float* __restrict__ V,
    ushort_t* __restrict__ Kb, ushort_t* __restrict__ Vt,
    int* __restrict__ cnt, int S, int jtiles)
{
    __shared__ ushort_t T[64 * 66];
    const int b  = blockIdx.x / jtiles;
    const int jt = blockIdx.x % jtiles;
    const int j0 = jt * 64;
    const int tid = threadIdx.x;

    if (blockIdx.x == 0 && tid == 0) *cnt = 0;

    // ---- K: elementwise cvt of this 64x64 tile ----
    {
        const int jj = tid >> 2, d0 = (tid & 3) * 16;
        const float* src = K + ((size_t)b * S + j0 + jj) * 64 + d0;
        f32x4 k0 = *(const f32x4a*)(src),     k1 = *(const f32x4a*)(src + 4);
        f32x4 k2 = *(const f32x4a*)(src + 8), k3 = *(const f32x4a*)(src + 12);
        u32x4 w0, w1;
#pragma unroll
        for (int k = 0; k < 2; ++k) {
            w0[k]   = (unsigned)f2bf(k0[2*k]) | ((unsigned)f2bf(k0[2*k+1]) << 16);
            w0[k+2] = (unsigned)f2bf(k1[2*k]) | ((unsigned)f2bf(k1[2*k+1]) << 16);
            w1[k]   = (unsigned)f2bf(k2[2*k]) | ((unsigned)f2bf(k2[2*k+1]) << 16);
            w1[k+2] = (unsigned)f2bf(k3[2*k]) | ((unsigned)f2bf(k3[2*k+1]) << 16);
        }
        ushort_t* dst = Kb + ((size_t)b * S + j0 + jj) * 64 + d0;
        *(u32x4a*)dst = w0;
        *(u32x4a*)(dst + 8) = w1;
    }

    // ---- V: transpose this 64x64 tile via LDS -> tile-major Vt ----
    {
        const float* Vb = V + ((size_t)b * S + j0) * 64;
#pragma unroll
        for (int p = 0; p < 4; ++p) {
            int jj = p * 16 + (tid >> 4), d4 = (tid & 15) * 4;
            f32x4 v = *(const f32x4a*)(Vb + (size_t)jj * 64 + d4);
#pragma unroll
            for (int k = 0; k < 4; ++k) T[(d4 + k) * 66 + jj] = f2bf(v[k]);
        }
        __syncthreads();
        const int d = tid >> 2, j16 = (tid & 3) * 16;
        ushort_t* dst = Vt + ((size_t)(b * jtiles + jt)) * 4096 + d * 64 + j16;
        u32x4 w0, w1;
#pragma unroll
        for (int k = 0; k < 4; ++k) {
            w0[k] = (unsigned)T[d*66 + j16 + 2*k]     | ((unsigned)T[d*66 + j16 + 2*k + 1] << 16);
            w1[k] = (unsigned)T[d*66 + j16 + 8 + 2*k] | ((unsigned)T[d*66 + j16 + 9 + 2*k] << 16);
        }
        *(u32x4a*)dst = w0;
        *(u32x4a*)(dst + 8) = w1;
    }
}

// ---------- persistent attention kernel: q-tile PAIRS ----------
// Each 256-thread block (4 waves) processes TWO consecutive q-tiles of one
// batch per grabbed item (atomicAdd(cnt,2); qtiles even -> same batch), so
// every 16 KB K/V tile DMA feeds 2x the MFMA work: total DMA traffic halves
// (~270 -> ~135 MB) while keeping round-6's per-block DMA geometry.
// Pipeline: 4 LDS buffers, 3-deep prefetch, vmcnt(12)/(8)/(4)/(0) ->
// 2 blocks/CU x 4 waves x 12 KB = 96 KB/CU in flight (same depth as the
// 71 us round-6 kernel; round 5 regressed because its depth halved).
// All fragment math identical to the verified round-6 body.
__global__ __launch_bounds__(256, 2) void attn_persist(
    const float* __restrict__ Q, const ushort_t* __restrict__ Kb,
    const ushort_t* __restrict__ Vt, const int* __restrict__ VL,
    float* __restrict__ O, int* __restrict__ cnt,
    int NB, int S, int qtiles, int nitems)
{
    __shared__ __align__(16) ushort_t Kbuf[4][64 * 64];
    __shared__ __align__(16) ushort_t Vbuf[4][64 * 64];
    __shared__ int order_s[64];
    __shared__ int item_s;

    const int tid  = threadIdx.x;
    const int wave = tid >> 6;
    const int lane = tid & 63;
    const int qd   = lane >> 4;
    const int c    = lane & 15;
    const int q8   = qd * 8;

    // ---- LPT: sort batches by VL descending (once per block) ----
    if (tid < NB && NB <= 64) {
        const int myL = VL[tid];
        int rank = 0;
        for (int j = 0; j < NB; ++j) {
            const int Lj = VL[j];
            rank += (Lj > myL) || (Lj == myL && j < tid);
        }
        order_s[rank] = tid;
    }
    __syncthreads();

    // ---- fixed per-thread DMA lane geometry ----
    const int r0 = wave * 16 + (lane >> 3);
    const int r1 = r0 + 8;
    const int bdp = lane & 7;
    const int swz0 = ((bdp - r0) & 7) * 16;
    const int swz1 = ((bdp - r1) & 7) * 16;
    const int ldsoff0 = wave * 1024;          // ushort units
    const int ldsoff1 = ldsoff0 + 512;

    // K-row permutation for the DMA source (LDS stays linear)
    const int pr0 = ((r0 >> 4) & 1) * 32 + ((r0 >> 2) & 3) * 8 + ((r0 >> 5) & 1) * 4 + (r0 & 3);
    const int pr1 = ((r1 >> 4) & 1) * 32 + ((r1 >> 2) & 3) * 8 + ((r1 >> 5) & 1) * 4 + (r1 & 3);

    // fragment read offsets (bytes, lane-constant)
    int off[2][4];
#pragma unroll
    for (int x = 0; x < 2; ++x)
#pragma unroll
        for (int y = 0; y < 4; ++y) {
            const int row = y * 16 + c;
            off[x][y] = row * 128 + (((x * 4 + qd) + row) & 7) * 16;
        }

    const float qs = 0.125f * 1.4426950408889634f;  // 1/sqrt(64)*log2(e)
    const f32x4 zero4 = {0.0f, 0.0f, 0.0f, 0.0f};

    for (;;) {
        if (tid == 0) item_s = atomicAdd(cnt, 2);
        __syncthreads();
        const int it = item_s;
        if (it >= nitems) break;

        const int b   = order_s[it / qtiles];
        const int qtA = it % qtiles;            // it even, qtiles even -> qtA,qtA+1 same batch
        const int qrow0A = qtA * 64 + wave * 16;
        const int qrow0B = qrow0A + 64;
        const int L   = VL[b];
        const int nkt = (L + BC - 1) / BC;

        // ---- Q raw loads FIRST (oldest VMEM ops of this item) ----
        f32x4 qaA[2], qbA[2], qaB[2], qbB[2];
        {
            const float* QbA = Q + ((size_t)b * S + qrow0A) * 64;
            const float* QbB = Q + ((size_t)b * S + qrow0B) * 64;
#pragma unroll
            for (int kc = 0; kc < 2; ++kc) {
                const float* pA = QbA + c * 64 + kc * 32 + q8;
                const float* pB = QbB + c * 64 + kc * 32 + q8;
                qaA[kc] = *(const f32x4a*)pA;
                qbA[kc] = *(const f32x4a*)(pA + 4);
                qaB[kc] = *(const f32x4a*)pB;
                qbB[kc] = *(const f32x4a*)(pB + 4);
            }
        }

        // ---- per-item DMA bases; issue tiles 0..2 ----
        const char* KbB_ = (const char*)(Kb + (size_t)b * S * 64);
        const char* VtB_ = (const char*)(Vt + (size_t)b * S * 64);   // tile-major
        const char* kg0 = KbB_ + pr0 * 128 + swz0;             // + kt*8192
        const char* kg1 = KbB_ + pr1 * 128 + swz1;
        const char* vg0 = VtB_ + r0 * 128 + swz0;              // + kt*8192
        const char* vg1 = VtB_ + r1 * 128 + swz1;

        dma16(kg0, Kbuf[0] + ldsoff0);
        dma16(kg1, Kbuf[0] + ldsoff1);
        dma16(vg0, Vbuf[0] + ldsoff0);
        dma16(vg1, Vbuf[0] + ldsoff1);
        if (nkt > 1) {
            dma16(kg0 + 8192, Kbuf[1] + ldsoff0);
            dma16(kg1 + 8192, Kbuf[1] + ldsoff1);
            dma16(vg0 + 8192, Vbuf[1] + ldsoff0);
            dma16(vg1 + 8192, Vbuf[1] + ldsoff1);
        }
        if (nkt > 2) {
            dma16(kg0 + 16384, Kbuf[2] + ldsoff0);
            dma16(kg1 + 16384, Kbuf[2] + ldsoff1);
            dma16(vg0 + 16384, Vbuf[2] + ldsoff0);
            dma16(vg1 + 16384, Vbuf[2] + ldsoff1);
        }

        // ---- pack Q fragments (compiler waits vmcnt(<=12): Q only) ----
        short8 qfA[2], qfB[2];
#pragma unroll
        for (int kc = 0; kc < 2; ++kc) {
            short8 fA, fB;
#pragma unroll
            for (int k = 0; k < 4; ++k) {
                fA[k]   = (short)f2bf(qaA[kc][k] * qs);
                fA[k+4] = (short)f2bf(qbA[kc][k] * qs);
                fB[k]   = (short)f2bf(qaB[kc][k] * qs);
                fB[k+4] = (short)f2bf(qbB[kc][k] * qs);
            }
            qfA[kc] = fA;
            qfB[kc] = fB;
        }

        f32x4 oaccA[4], oaccB[4];
#pragma unroll
        for (int dt = 0; dt < 4; ++dt) { oaccA[dt] = zero4; oaccB[dt] = zero4; }
        float rsA0 = 0.0f, rsA1 = 0.0f, rsB0 = 0.0f, rsB1 = 0.0f;

        for (int kt = 0; kt < nkt; ++kt) {
            const int j0 = kt * BC;
            const ushort_t* Kt  = Kbuf[kt & 3];
            const ushort_t* Vb_ = Vbuf[kt & 3];

            if (kt + 3 < nkt) {
                const int pre = (kt + 3) & 3;
                const size_t ko = (size_t)(kt + 3) * 8192;
                dma16(kg0 + ko, Kbuf[pre] + ldsoff0);
                dma16(kg1 + ko, Kbuf[pre] + ldsoff1);
                dma16(vg0 + ko, Vbuf[pre] + ldsoff0);
                dma16(vg1 + ko, Vbuf[pre] + ldsoff1);
                BAR_VM12();  // tile kt resident; kt+1..kt+3 (12) stay in flight
            } else if (kt + 2 < nkt) {
                BAR_VM8();
            } else if (kt + 1 < nkt) {
                BAR_VM4();
            } else {
                BAR_VM0();
            }

            const int lim = L - j0 - q8;

            // ================= half A =================
            {
                f32x4 sacc[4];
#pragma unroll
                for (int nt = 0; nt < 4; ++nt) sacc[nt] = zero4;
                __builtin_amdgcn_s_setprio(1);
#pragma unroll
                for (int kc = 0; kc < 2; ++kc) {
#pragma unroll
                    for (int nt = 0; nt < 4; ++nt) {
                        short8 kf = *(const short8a*)((const char*)Kt + off[kc][nt]);
                        sacc[nt] = __builtin_amdgcn_mfma_f32_16x16x32_bf16(kf, qfA[kc], sacc[nt], 0, 0, 0);
                    }
                }
                __builtin_amdgcn_s_setprio(0);

                float p[4][4];
#pragma unroll
                for (int nt = 0; nt < 4; ++nt) {
                    const int kb2 = (nt & 1) * 32 + ((nt >> 1) << 2);
#pragma unroll
                    for (int r = 0; r < 4; ++r) {
                        const bool valid = (kb2 + r < lim);
                        const float e = valid ? exp2f(sacc[nt][r]) : 0.0f;
                        p[nt][r] = e;
                        if (nt & 1) rsA1 += e; else rsA0 += e;
                    }
                }

                __builtin_amdgcn_s_setprio(1);
#pragma unroll
                for (int jc = 0; jc < 2; ++jc) {
                    u32x4 w;
                    w[0] = (unsigned)f2bf(p[jc][0])     | ((unsigned)f2bf(p[jc][1])     << 16);
                    w[1] = (unsigned)f2bf(p[jc][2])     | ((unsigned)f2bf(p[jc][3])     << 16);
                    w[2] = (unsigned)f2bf(p[jc + 2][0]) | ((unsigned)f2bf(p[jc + 2][1]) << 16);
                    w[3] = (unsigned)f2bf(p[jc + 2][2]) | ((unsigned)f2bf(p[jc + 2][3]) << 16);
                    const short8 pf = __builtin_bit_cast(short8, w);
#pragma unroll
                    for (int dt = 0; dt < 4; ++dt) {
                        short8 vf = *(const short8a*)((const char*)Vb_ + off[jc][dt]);
                        oaccA[dt] = __builtin_amdgcn_mfma_f32_16x16x32_bf16(pf, vf, oaccA[dt], 0, 0, 0);
                    }
                }
                __builtin_amdgcn_s_setprio(0);
            }

            // ================= half B =================
            {
                f32x4 sacc[4];
#pragma unroll
                for (int nt = 0; nt < 4; ++nt) sacc[nt] = zero4;
                __builtin_amdgcn_s_setprio(1);
#pragma unroll
                for (int kc = 0; kc < 2; ++kc) {
#pragma unroll
                    for (int nt = 0; nt < 4; ++nt) {
                        short8 kf = *(const short8a*)((const char*)Kt + off[kc][nt]);
                        sacc[nt] = __builtin_amdgcn_mfma_f32_16x16x32_bf16(kf, qfB[kc], sacc[nt], 0, 0, 0);
                    }
                }
                __builtin_amdgcn_s_setprio(0);

                float p[4][4];
#pragma unroll
                for (int nt = 0; nt < 4; ++nt) {
                    const int kb2 = (nt & 1) * 32 + ((nt >> 1) << 2);
#pragma unroll
                    for (int r = 0; r < 4; ++r) {
                        const bool valid = (kb2 + r < lim);
                        const float e = valid ? exp2f(sacc[nt][r]) : 0.0f;
                        p[nt][r] = e;
                        if (nt & 1) rsB1 += e; else rsB0 += e;
                    }
                }

                __builtin_amdgcn_s_setprio(1);
#pragma unroll
                for (int jc = 0; jc < 2; ++jc) {
                    u32x4 w;
                    w[0] = (unsigned)f2bf(p[jc][0])     | ((unsigned)f2bf(p[jc][1])     << 16);
                    w[1] = (unsigned)f2bf(p[jc][2])     | ((unsigned)f2bf(p[jc][3])     << 16);
                    w[2] = (unsigned)f2bf(p[jc + 2][0]) | ((unsigned)f2bf(p[jc + 2][1]) << 16);
                    w[3] = (unsigned)f2bf(p[jc + 2][2]) | ((unsigned)f2bf(p[jc + 2][3]) << 16);
                    const short8 pf = __builtin_bit_cast(short8, w);
#pragma unroll
                    for (int dt = 0; dt < 4; ++dt) {
                        short8 vf = *(const short8a*)((const char*)Vb_ + off[jc][dt]);
                        oaccB[dt] = __builtin_amdgcn_mfma_f32_16x16x32_bf16(pf, vf, oaccB[dt], 0, 0, 0);
                    }
                }
                __builtin_amdgcn_s_setprio(0);
            }

            BAR_LGKM();   // all waves done reading buf[kt] before its reuse
        }

        // ---- finalize both q-tiles ----
        {
            float rsum = rsA0 + rsA1;
            rsum += __shfl_xor(rsum, 16);
            rsum += __shfl_xor(rsum, 32);
            const float inv = 1.0f / rsum;
#pragma unroll
            for (int r = 0; r < 4; ++r) {
                const float invr = __shfl(inv, (lane & 48) | (qd * 4 + r));
                const int row = qrow0A + qd * 4 + r;
                float* dst = O + ((size_t)b * S + row) * 64;
#pragma unroll
                for (int dt = 0; dt < 4; ++dt)
                    dst[dt * 16 + c] = oaccA[dt][r] * invr;
            }
        }
        {
            float rsum = rsB0 + rsB1;
            rsum += __shfl_xor(rsum, 16);
            rsum += __shfl_xor(rsum, 32);
            const float inv = 1.0f / rsum;
#pragma unroll
            for (int r = 0; r < 4; ++r) {
                const float invr = __shfl(inv, (lane & 48) | (qd * 4 + r));
                const int row = qrow0B + qd * 4 + r;
                float* dst = O + ((size_t)b * S + row) * 64;
#pragma unroll
                for (int dt = 0; dt < 4; ++dt)
                    dst[dt * 16 + c] = oaccB[dt][r] * invr;
            }
        }
    }
}

// ---------- fallback (no-workspace path) ----------
__global__ __launch_bounds__(256, 4) void attn_mono(
    const float* __restrict__ Q, const float* __restrict__ K,
    const float* __restrict__ V, const int* __restrict__ VL,
    float* __restrict__ O, int NB, int S)
{
    __shared__ ushort_t Ksh[BC * PRP];
    __shared__ ushort_t Vsh[64 * PRP];
    __shared__ ushort_t Psh[4 * 16 * PRP];
    const int tid = threadIdx.x, wave = tid >> 6, lane = tid & 63;
    const int qd = lane >> 4, c = lane & 15, q8 = qd * 8;
    const int bid = blockIdx.x;
    const int b = (bid & 7) | (((bid >> 3) & 3) << 3);
    const int qt = bid >> 5;
    const int qrow0 = qt * 64 + wave * 16;
    const int L = VL[b];
    const int nkt = (L + BC - 1) / BC;
    const size_t bbase = (size_t)b * S * 64;
    const int kj = tid >> 2, kd = (tid & 3) * 16;
    const int vp = tid & 31, vd = (tid >> 5) * 8;
    const float qs = 0.125f * 1.4426950408889634f;
    short8 qf[2];
    {
        const float* Qb = Q + bbase + (size_t)qrow0 * 64;
#pragma unroll
        for (int kc = 0; kc < 2; ++kc) {
            const float* p = Qb + c * 64 + kc * 32 + q8;
            f32x4 a = *(const f32x4a*)p;
            f32x4 bq = *(const f32x4a*)(p + 4);
            short8 f;
#pragma unroll
            for (int k = 0; k < 4; ++k) { f[k] = (short)f2bf(a[k]*qs); f[k+4] = (short)f2bf(bq[k]*qs); }
            qf[kc] = f;
        }
    }
    const f32x4 zero4 = {0.0f, 0.0f, 0.0f, 0.0f};
    f32x4 oacc[4];
#pragma unroll
    for (int dt = 0; dt < 4; ++dt) oacc[dt] = zero4;
    float lrow[4] = {0, 0, 0, 0};
    ushort_t* Pw = Psh + wave * (16 * PRP);
    for (int kt = 0; kt < nkt; ++kt) {
        const int j0 = kt * BC;
        __syncthreads();
        {
            const float* src = K + bbase + (size_t)(j0 + kj) * 64 + kd;
            f32x4 k0 = *(const f32x4a*)(src), k1 = *(const f32x4a*)(src + 4);
            f32x4 k2 = *(const f32x4a*)(src + 8), k3 = *(const f32x4a*)(src + 12);
            u32x4 w0, w1;
#pragma unroll
            for (int k = 0; k < 2; ++k) {
                w0[k]   = (unsigned)f2bf(k0[2*k]) | ((unsigned)f2bf(k0[2*k+1]) << 16);
                w0[k+2] = (unsigned)f2bf(k1[2*k]) | ((unsigned)f2bf(k1[2*k+1]) << 16);
                w1[k]   = (unsigned)f2bf(k2[2*k]) | ((unsigned)f2bf(k2[2*k+1]) << 16);
                w1[k+2] = (unsigned)f2bf(k3[2*k]) | ((unsigned)f2bf(k3[2*k+1]) << 16);
            }
            *(u32x4a*)&Ksh[kj * PRP + kd] = w0;
            *(u32x4a*)&Ksh[kj * PRP + kd + 8] = w1;
        }
        {
            const float* src = V + bbase + (size_t)(j0 + 2 * vp) * 64 + vd;
            f32x4 a0 = *(const f32x4a*)(src), a1 = *(const f32x4a*)(src + 4);
            f32x4 b0 = *(const f32x4a*)(src + 64), b1 = *(const f32x4a*)(src + 68);
#pragma unroll
            for (int kk = 0; kk < 8; ++kk) {
                float av = (kk < 4) ? a0[kk & 3] : a1[kk & 3];
                float bv = (kk < 4) ? b0[kk & 3] : b1[kk & 3];
                *(unsigned __attribute__((may_alias))*)&Vsh[(vd + kk) * PRP + 2 * vp] =
                    (unsigned)f2bf(av) | ((unsigned)f2bf(bv) << 16);
            }
        }
        __syncthreads();
        f32x4 sacc[4];
#pragma unroll
        for (int nt = 0; nt < 4; ++nt) sacc[nt] = zero4;
#pragma unroll
        for (int kc = 0; kc < 2; ++kc)
#pragma unroll
            for (int nt = 0; nt < 4; ++nt) {
                short8 kf = *(const short8a*)&Ksh[(nt * 16 + c) * PRP + kc * 32 + q8];
                sacc[nt] = __builtin_amdgcn_mfma_f32_16x16x32_bf16(qf[kc], kf, sacc[nt], 0, 0, 0);
            }
#pragma unroll
        for (int nt = 0; nt < 4; ++nt) {
            const bool valid = (j0 + nt * 16 + c) < L;
#pragma unroll
            for (int r = 0; r < 4; ++r) {
                float p = valid ? exp2f(sacc[nt][r]) : 0.0f;
                lrow[r] += p;
                Pw[(qd * 4 + r) * PRP + nt * 16 + c] = f2bf(p);
            }
        }
#pragma unroll
        for (int jc = 0; jc < 2; ++jc) {
            short8 pf = *(const short8a*)&Pw[c * PRP + jc * 32 + q8];
#pragma unroll
            for (int dt = 0; dt < 4; ++dt) {
                short8 vf = *(const short8a*)&Vsh[(dt * 16 + c) * PRP + jc * 32 + q8];
                oacc[dt] = __builtin_amdgcn_mfma_f32_16x16x32_bf16(pf, vf, oacc[dt], 0, 0, 0);
            }
        }
    }
#pragma unroll
    for (int r = 0; r < 4; ++r) {
        float ls = lrow[r];
        ls += __shfl_xor(ls, 1); ls += __shfl_xor(ls, 2);
        ls += __shfl_xor(ls, 4); ls += __shfl_xor(ls, 8);
        const float inv = 1.0f / ls;
        const int row = qrow0 + qd * 4 + r;
        float* dst = O + bbase + (size_t)row * 64;
#pragma unroll
        for (int dt = 0; dt < 4; ++dt) dst[dt * 16 + c] = oacc[dt][r] * inv;
    }
}

extern "C" void kernel_launch(void* const* d_in, const int* in_sizes, int n_in,
                              void* d_out, int out_size, void* d_ws, size_t ws_size,
                              hipStream_t stream) {
    const float* Q = (const float*)d_in[0];
    const float* K = (const float*)d_in[1];
    const float* V = (const float*)d_in[2];
    const int*  VL = (const int*)d_in[3];
    float*      Op = (float*)d_out;

    const int NB = in_sizes[3];               // 32
    const int S  = in_sizes[0] / (NB * 64);   // 2048
    const int qtiles = S / 64;                // 32
    const int jtiles = S / 64;
    const size_t nelem = (size_t)NB * S * 64;
    const size_t bf_bytes = nelem * 2;        // 8.39 MB each

    if (ws_size >= 256 + 2 * bf_bytes && NB <= 64 && (qtiles % 2) == 0) {
        int* cnt = (int*)d_ws;
        ushort_t* Kb = (ushort_t*)((char*)d_ws + 256);
        ushort_t* Vt = (ushort_t*)((char*)d_ws + 256 + bf_bytes);
        prep_kv<<<dim3(NB * jtiles), dim3(256), 0, stream>>>(K, V, Kb, Vt, cnt, S, jtiles);
        const int nitems = NB * qtiles;
        const int npairs = nitems / 2;
        const int grid = npairs < 512 ? npairs : 512;
        attn_persist<<<dim3(grid), dim3(256), 0, stream>>>(
            Q, Kb, Vt, VL, Op, cnt, NB, S, qtiles, nitems);
    } else {
        attn_mono<<<dim3(NB * qtiles), dim3(256), 0, stream>>>(Q, K, V, VL, Op, NB, S);
    }
}

// Round 10
// 152.137 us; speedup vs baseline: 1.1026x; 1.1026x over previous
//
#include <hip/hip_runtime.h>

typedef unsigned short ushort_t;
typedef short short8 __attribute__((ext_vector_type(8)));
typedef float f32x4 __attribute__((ext_vector_type(4)));
typedef unsigned int u32x4 __attribute__((ext_vector_type(4)));

typedef f32x4 f32x4a __attribute__((may_alias));
typedef u32x4 u32x4a __attribute__((may_alias));
typedef short8 short8a __attribute__((may_alias));

#define BC 64
#define PRP 74   // P-buffer pitch for fallback kernel

#define BAR_LGKM() asm volatile("s_waitcnt lgkmcnt(0)\n\ts_barrier" ::: "memory")
#define BAR_VM8()  asm volatile("s_waitcnt vmcnt(8)\n\ts_barrier" ::: "memory")
#define BAR_VM4()  asm volatile("s_waitcnt vmcnt(4)\n\ts_barrier" ::: "memory")
#define BAR_VM0()  asm volatile("s_waitcnt vmcnt(0)\n\ts_barrier" ::: "memory")

__device__ __forceinline__ ushort_t f2bf(float x) {
    unsigned u = __float_as_uint(x);
    u = (u + 0x7fffu + ((u >> 16) & 1u)) >> 16;   // RNE
    return (ushort_t)u;
}

__device__ __forceinline__ void dma16(const void* g, void* lds) {
    __builtin_amdgcn_global_load_lds(
        (const __attribute__((address_space(1))) unsigned int*)g,
        (__attribute__((address_space(3))) unsigned int*)lds, 16, 0, 0);
}

// ---------- fused pre-pass: K -> bf16 (same layout), V -> bf16 transposed ----------
// Vt is TILE-MAJOR: [b][jtile][d(64)][j(64)]. Also zeroes the 8 group counters.
__global__ __launch_bounds__(256) void prep_kv(
    const float* __restrict__ K, const float* __restrict__ V,
    ushort_t* __restrict__ Kb, ushort_t* __restrict__ Vt,
    int* __restrict__ cnt, int S, int jtiles)
{
    __shared__ ushort_t T[64 * 66];
    const int b  = blockIdx.x / jtiles;
    const int jt = blockIdx.x % jtiles;
    const int j0 = jt * 64;
    const int tid = threadIdx.x;

    if (blockIdx.x == 0 && tid < 8) cnt[tid] = 0;

    // ---- K: elementwise cvt of this 64x64 tile ----
    {
        const int jj = tid >> 2, d0 = (tid & 3) * 16;
        const float* src = K + ((size_t)b * S + j0 + jj) * 64 + d0;
        f32x4 k0 = *(const f32x4a*)(src),     k1 = *(const f32x4a*)(src + 4);
        f32x4 k2 = *(const f32x4a*)(src + 8), k3 = *(const f32x4a*)(src + 12);
        u32x4 w0, w1;
#pragma unroll
        for (int k = 0; k < 2; ++k) {
            w0[k]   = (unsigned)f2bf(k0[2*k]) | ((unsigned)f2bf(k0[2*k+1]) << 16);
            w0[k+2] = (unsigned)f2bf(k1[2*k]) | ((unsigned)f2bf(k1[2*k+1]) << 16);
            w1[k]   = (unsigned)f2bf(k2[2*k]) | ((unsigned)f2bf(k2[2*k+1]) << 16);
            w1[k+2] = (unsigned)f2bf(k3[2*k]) | ((unsigned)f2bf(k3[2*k+1]) << 16);
        }
        ushort_t* dst = Kb + ((size_t)b * S + j0 + jj) * 64 + d0;
        *(u32x4a*)dst = w0;
        *(u32x4a*)(dst + 8) = w1;
    }

    // ---- V: transpose this 64x64 tile via LDS -> tile-major Vt ----
    {
        const float* Vb = V + ((size_t)b * S + j0) * 64;
#pragma unroll
        for (int p = 0; p < 4; ++p) {
            int jj = p * 16 + (tid >> 4), d4 = (tid & 15) * 4;
            f32x4 v = *(const f32x4a*)(Vb + (size_t)jj * 64 + d4);
#pragma unroll
            for (int k = 0; k < 4; ++k) T[(d4 + k) * 66 + jj] = f2bf(v[k]);
        }
        __syncthreads();
        const int d = tid >> 2, j16 = (tid & 3) * 16;
        ushort_t* dst = Vt + ((size_t)(b * jtiles + jt)) * 4096 + d * 64 + j16;
        u32x4 w0, w1;
#pragma unroll
        for (int k = 0; k < 4; ++k) {
            w0[k] = (unsigned)T[d*66 + j16 + 2*k]     | ((unsigned)T[d*66 + j16 + 2*k + 1] << 16);
            w1[k] = (unsigned)T[d*66 + j16 + 8 + 2*k] | ((unsigned)T[d*66 + j16 + 9 + 2*k] << 16);
        }
        *(u32x4a*)dst = w0;
        *(u32x4a*)(dst + 8) = w1;
    }
}

// ---------- persistent attention kernel (round-6 geometry + XCD-local queues) ----------
// Geometry (best measured, 71 us): 256 thr / 4 waves, 3 LDS buffers, 2-deep
// DMA prefetch, vmcnt(8)/(4)/(0), pi-permuted K rows folded into DMA
// addressing, swapped-operand QK^T -> in-register softmax -> register-packed
// PV, max-free exp2 softmax, Q-load hoisted above prologue DMAs.
//
// NEW (L2 locality): 8 work queues, one per XCD. Block's group
// g = blockIdx.x % 8 (dispatch round-robins XCDs). Batches are snake-dealt
// over groups by VL-sorted rank (rank = kb*8 + (kb odd ? 7-g : g)), so each
// group of 96 blocks marches batch-major through its own 4 batches: the hot
// K/V working set per XCD is ~1 batch (1 MB bf16) -> L2-resident instead of
// L3-served. Mapping wrong => perf-neutral; correctness unaffected.
//
// NEW (VALU): P-pack uses round-half-up add+shift/mask (5 ops/pair) instead
// of the 12-op RNE pair; zeros stay zero; error < bf16 lsb, unbiased.
__global__ __launch_bounds__(256, 3) void attn_persist(
    const float* __restrict__ Q, const ushort_t* __restrict__ Kb,
    const ushort_t* __restrict__ Vt, const int* __restrict__ VL,
    float* __restrict__ O, int* __restrict__ cnt,
    int NB, int S, int qtiles)
{
    __shared__ __align__(16) ushort_t Kbuf[3][64 * 64];
    __shared__ __align__(16) ushort_t Vbuf[3][64 * 64];
    __shared__ int order_s[64];
    __shared__ int item_s;

    const int tid  = threadIdx.x;
    const int wave = tid >> 6;
    const int lane = tid & 63;
    const int qd   = lane >> 4;
    const int c    = lane & 15;
    const int q8   = qd * 8;

    const int ngrp = (NB >= 8 && (NB % 8) == 0) ? 8 : 1;
    const int bpg  = NB / ngrp;               // batches per group
    const int ipg  = bpg * qtiles;            // items per group
    const int g    = blockIdx.x % ngrp;

    // ---- LPT: sort batches by VL descending (once per block) ----
    if (tid < NB && NB <= 64) {
        const int myL = VL[tid];
        int rank = 0;
        for (int j = 0; j < NB; ++j) {
            const int Lj = VL[j];
            rank += (Lj > myL) || (Lj == myL && j < tid);
        }
        order_s[rank] = tid;
    }
    __syncthreads();

    // ---- fixed per-thread DMA lane geometry ----
    const int r0 = wave * 16 + (lane >> 3);
    const int r1 = r0 + 8;
    const int bdp = lane & 7;
    const int swz0 = ((bdp - r0) & 7) * 16;
    const int swz1 = ((bdp - r1) & 7) * 16;
    const int ldsoff0 = wave * 1024;          // ushort units
    const int ldsoff1 = ldsoff0 + 512;

    // K-row permutation for the DMA source (LDS stays linear)
    const int pr0 = ((r0 >> 4) & 1) * 32 + ((r0 >> 2) & 3) * 8 + ((r0 >> 5) & 1) * 4 + (r0 & 3);
    const int pr1 = ((r1 >> 4) & 1) * 32 + ((r1 >> 2) & 3) * 8 + ((r1 >> 5) & 1) * 4 + (r1 & 3);

    // fragment read offsets (bytes, lane-constant)
    int off[2][4];
#pragma unroll
    for (int x = 0; x < 2; ++x)
#pragma unroll
        for (int y = 0; y < 4; ++y) {
            const int row = y * 16 + c;
            off[x][y] = row * 128 + (((x * 4 + qd) + row) & 7) * 16;
        }

    const float qs = 0.125f * 1.4426950408889634f;  // 1/sqrt(64)*log2(e)
    const f32x4 zero4 = {0.0f, 0.0f, 0.0f, 0.0f};

    for (;;) {
        if (tid == 0) item_s = atomicAdd(cnt + g, 1);
        __syncthreads();
        const int it = item_s;
        if (it >= ipg) break;

        // snake-deal decode: group g, round kb -> batch rank
        const int kb = it / qtiles;
        const int qt = it % qtiles;
        const int rank = kb * ngrp + ((kb & 1) ? (ngrp - 1 - g) : g);
        const int b  = order_s[rank];
        const int qrow0 = qt * 64 + wave * 16;
        const int L   = VL[b];
        const int nkt = (L + BC - 1) / BC;

        // ---- Q raw loads FIRST (oldest VMEM ops of this item) ----
        f32x4 qa[2], qb[2];
        {
            const float* Qb = Q + ((size_t)b * S + qrow0) * 64;
#pragma unroll
            for (int kc = 0; kc < 2; ++kc) {
                const float* qp = Qb + c * 64 + kc * 32 + q8;
                qa[kc] = *(const f32x4a*)qp;
                qb[kc] = *(const f32x4a*)(qp + 4);
            }
        }

        // ---- per-item DMA bases; issue tile-0/1 DMAs ----
        const char* KbB = (const char*)(Kb + (size_t)b * S * 64);
        const char* VtB = (const char*)(Vt + (size_t)b * S * 64);   // tile-major
        const char* kg0 = KbB + pr0 * 128 + swz0;             // + kt*8192
        const char* kg1 = KbB + pr1 * 128 + swz1;
        const char* vg0 = VtB + r0 * 128 + swz0;              // + kt*8192
        const char* vg1 = VtB + r1 * 128 + swz1;

        dma16(kg0, Kbuf[0] + ldsoff0);
        dma16(kg1, Kbuf[0] + ldsoff1);
        dma16(vg0, Vbuf[0] + ldsoff0);
        dma16(vg1, Vbuf[0] + ldsoff1);
        if (nkt > 1) {
            dma16(kg0 + 8192, Kbuf[1] + ldsoff0);
            dma16(kg1 + 8192, Kbuf[1] + ldsoff1);
            dma16(vg0 + 8192, Vbuf[1] + ldsoff0);
            dma16(vg1 + 8192, Vbuf[1] + ldsoff1);
        }

        // ---- pack Q fragments (compiler waits vmcnt(<=8): Q only) ----
        short8 qf[2];
#pragma unroll
        for (int kc = 0; kc < 2; ++kc) {
            short8 f;
#pragma unroll
            for (int k = 0; k < 4; ++k) {
                f[k]   = (short)f2bf(qa[kc][k] * qs);
                f[k+4] = (short)f2bf(qb[kc][k] * qs);
            }
            qf[kc] = f;
        }

        f32x4 oacc[4];
#pragma unroll
        for (int dt = 0; dt < 4; ++dt) oacc[dt] = zero4;
        float rs0 = 0.0f, rs1 = 0.0f;   // row-sum for q = c (this lane's query)

        int cur = 0;                    // kt % 3
        for (int kt = 0; kt < nkt; ++kt) {
            const int j0 = kt * BC;
            const ushort_t* Kt  = Kbuf[cur];
            const ushort_t* Vb_ = Vbuf[cur];

            if (kt + 2 < nkt) {
                const int pre = (cur == 0) ? 2 : cur - 1;   // (kt+2) % 3
                const size_t ko = (size_t)(kt + 2) * 8192;
                dma16(kg0 + ko, Kbuf[pre] + ldsoff0);
                dma16(kg1 + ko, Kbuf[pre] + ldsoff1);
                dma16(vg0 + ko, Vbuf[pre] + ldsoff0);
                dma16(vg1 + ko, Vbuf[pre] + ldsoff1);
                BAR_VM8();   // tile kt resident; kt+1,kt+2's 8 stay in flight
            } else if (kt + 1 < nkt) {
                BAR_VM4();
            } else {
                BAR_VM0();
            }

            // ---- S^T = K Q^T : 8 MFMAs (log2 units) ----
            f32x4 sacc[4];
#pragma unroll
            for (int nt = 0; nt < 4; ++nt) sacc[nt] = zero4;
            __builtin_amdgcn_s_setprio(1);
#pragma unroll
            for (int kc = 0; kc < 2; ++kc) {
#pragma unroll
                for (int nt = 0; nt < 4; ++nt) {
                    short8 kf = *(const short8a*)((const char*)Kt + off[kc][nt]);
                    sacc[nt] = __builtin_amdgcn_mfma_f32_16x16x32_bf16(kf, qf[kc], sacc[nt], 0, 0, 0);
                }
            }
            __builtin_amdgcn_s_setprio(0);

            // ---- max-free softmax, fully in registers ----
            // sacc[nt][r] = S[q=c][key = j0 + qd*8 + (nt&1)*32 + (nt>>1)*4 + r]
            const int lim = L - j0 - q8;
            float p[4][4];
#pragma unroll
            for (int nt = 0; nt < 4; ++nt) {
                const int kb2 = (nt & 1) * 32 + ((nt >> 1) << 2);
#pragma unroll
                for (int r = 0; r < 4; ++r) {
                    const bool valid = (kb2 + r < lim);
                    const float e = valid ? exp2f(sacc[nt][r]) : 0.0f;
                    p[nt][r] = e;
                    if (nt & 1) rs1 += e; else rs0 += e;
                }
            }

            // ---- O += P V : PV A-fragment packed from registers ----
            // round-half-up bf16 pack: (bits+0x8000)>>16; zeros stay zero
            __builtin_amdgcn_s_setprio(1);
#pragma unroll
            for (int jc = 0; jc < 2; ++jc) {
                u32x4 w;
#pragma unroll
                for (int h = 0; h < 2; ++h) {
                    const float* pp = p[jc + 2 * h];
                    unsigned u0 = __float_as_uint(pp[0]) + 0x8000u;
                    unsigned u1 = __float_as_uint(pp[1]) + 0x8000u;
                    unsigned u2 = __float_as_uint(pp[2]) + 0x8000u;
                    unsigned u3 = __float_as_uint(pp[3]) + 0x8000u;
                    w[2*h]   = (u0 >> 16) | (u1 & 0xffff0000u);
                    w[2*h+1] = (u2 >> 16) | (u3 & 0xffff0000u);
                }
                const short8 pf = __builtin_bit_cast(short8, w);
#pragma unroll
                for (int dt = 0; dt < 4; ++dt) {
                    short8 vf = *(const short8a*)((const char*)Vb_ + off[jc][dt]);
                    oacc[dt] = __builtin_amdgcn_mfma_f32_16x16x32_bf16(pf, vf, oacc[dt], 0, 0, 0);
                }
            }
            __builtin_amdgcn_s_setprio(0);

            BAR_LGKM();   // all waves done reading buf[kt] before its reuse
            cur = (cur == 2) ? 0 : cur + 1;
        }

        // ---- finalize item ----
        float rsum = rs0 + rs1;
        rsum += __shfl_xor(rsum, 16);
        rsum += __shfl_xor(rsum, 32);
        const float inv = 1.0f / rsum;          // denom for q = c
#pragma unroll
        for (int r = 0; r < 4; ++r) {
            const float invr = __shfl(inv, (lane & 48) | (qd * 4 + r));
            const int row = qrow0 + qd * 4 + r;
            float* dst = O + ((size_t)b * S + row) * 64;
#pragma unroll
            for (int dt = 0; dt < 4; ++dt)
                dst[dt * 16 + c] = oacc[dt][r] * invr;
        }
    }
}

// ---------- fallback (no-workspace path) ----------
__global__ __launch_bounds__(256, 4) void attn_mono(
    const float* __restrict__ Q, const float* __restrict__ K,
    const float* __restrict__ V, const int* __restrict__ VL,
    float* __restrict__ O, int NB, int S)
{
    __shared__ ushort_t Ksh[BC * PRP];
    __shared__ ushort_t Vsh[64 * PRP];
    __shared__ ushort_t Psh[4 * 16 * PRP];
    const int tid = threadIdx.x, wave = tid >> 6, lane = tid & 63;
    const int qd = lane >> 4, c = lane & 15, q8 = qd * 8;
    const int bid = blockIdx.x;
    const int b = (bid & 7) | (((bid >> 3) & 3) << 3);
    const int qt = bid >> 5;
    const int qrow0 = qt * 64 + wave * 16;
    const int L = VL[b];
    const int nkt = (L + BC - 1) / BC;
    const size_t bbase = (size_t)b * S * 64;
    const int kj = tid >> 2, kd = (tid & 3) * 16;
    const int vp = tid & 31, vd = (tid >> 5) * 8;
    const float qs = 0.125f * 1.4426950408889634f;
    short8 qf[2];
    {
        const float* Qb = Q + bbase + (size_t)qrow0 * 64;
#pragma unroll
        for (int kc = 0; kc < 2; ++kc) {
            const float* p = Qb + c * 64 + kc * 32 + q8;
            f32x4 a = *(const f32x4a*)p;
            f32x4 bq = *(const f32x4a*)(p + 4);
            short8 f;
#pragma unroll
            for (int k = 0; k < 4; ++k) { f[k] = (short)f2bf(a[k]*qs); f[k+4] = (short)f2bf(bq[k]*qs); }
            qf[kc] = f;
        }
    }
    const f32x4 zero4 = {0.0f, 0.0f, 0.0f, 0.0f};
    f32x4 oacc[4];
#pragma unroll
    for (int dt = 0; dt < 4; ++dt) oacc[dt] = zero4;
    float lrow[4] = {0, 0, 0, 0};
    ushort_t* Pw = Psh + wave * (16 * PRP);
    for (int kt = 0; kt < nkt; ++kt) {
        const int j0 = kt * BC;
        __syncthreads();
        {
            const float* src = K + bbase + (size_t)(j0 + kj) * 64 + kd;
            f32x4 k0 = *(const f32x4a*)(src), k1 = *(const f32x4a*)(src + 4);
            f32x4 k2 = *(const f32x4a*)(src + 8), k3 = *(const f32x4a*)(src + 12);
            u32x4 w0, w1;
#pragma unroll
            for (int k = 0; k < 2; ++k) {
                w0[k]   = (unsigned)f2bf(k0[2*k]) | ((unsigned)f2bf(k0[2*k+1]) << 16);
                w0[k+2] = (unsigned)f2bf(k1[2*k]) | ((unsigned)f2bf(k1[2*k+1]) << 16);
                w1[k]   = (unsigned)f2bf(k2[2*k]) | ((unsigned)f2bf(k2[2*k+1]) << 16);
                w1[k+2] = (unsigned)f2bf(k3[2*k]) | ((unsigned)f2bf(k3[2*k+1]) << 16);
            }
            *(u32x4a*)&Ksh[kj * PRP + kd] = w0;
            *(u32x4a*)&Ksh[kj * PRP + kd + 8] = w1;
        }
        {
            const float* src = V + bbase + (size_t)(j0 + 2 * vp) * 64 + vd;
            f32x4 a0 = *(const f32x4a*)(src), a1 = *(const f32x4a*)(src + 4);
            f32x4 b0 = *(const f32x4a*)(src + 64), b1 = *(const f32x4a*)(src + 68);
#pragma unroll
            for (int kk = 0; kk < 8; ++kk) {
                float av = (kk < 4) ? a0[kk & 3] : a1[kk & 3];
                float bv = (kk < 4) ? b0[kk & 3] : b1[kk & 3];
                *(unsigned __attribute__((may_alias))*)&Vsh[(vd + kk) * PRP + 2 * vp] =
                    (unsigned)f2bf(av) | ((unsigned)f2bf(bv) << 16);
            }
        }
        __syncthreads();
        f32x4 sacc[4];
#pragma unroll
        for (int nt = 0; nt < 4; ++nt) sacc[nt] = zero4;
#pragma unroll
        for (int kc = 0; kc < 2; ++kc)
#pragma unroll
            for (int nt = 0; nt < 4; ++nt) {
                short8 kf = *(const short8a*)&Ksh[(nt * 16 + c) * PRP + kc * 32 + q8];
                sacc[nt] = __builtin_amdgcn_mfma_f32_16x16x32_bf16(qf[kc], kf, sacc[nt], 0, 0, 0);
            }
#pragma unroll
        for (int nt = 0; nt < 4; ++nt) {
            const bool valid = (j0 + nt * 16 + c) < L;
#pragma unroll
            for (int r = 0; r < 4; ++r) {
                float p = valid ? exp2f(sacc[nt][r]) : 0.0f;
                lrow[r] += p;
                Pw[(qd * 4 + r) * PRP + nt * 16 + c] = f2bf(p);
            }
        }
#pragma unroll
        for (int jc = 0; jc < 2; ++jc) {
            short8 pf = *(const short8a*)&Pw[c * PRP + jc * 32 + q8];
#pragma unroll
            for (int dt = 0; dt < 4; ++dt) {
                short8 vf = *(const short8a*)&Vsh[(dt * 16 + c) * PRP + jc * 32 + q8];
                oacc[dt] = __builtin_amdgcn_mfma_f32_16x16x32_bf16(pf, vf, oacc[dt], 0, 0, 0);
            }
        }
    }
#pragma unroll
    for (int r = 0; r < 4; ++r) {
        float ls = lrow[r];
        ls += __shfl_xor(ls, 1); ls += __shfl_xor(ls, 2);
        ls += __shfl_xor(ls, 4); ls += __shfl_xor(ls, 8);
        const float inv = 1.0f / ls;
        const int row = qrow0 + qd * 4 + r;
        float* dst = O + bbase + (size_t)row * 64;
#pragma unroll
        for (int dt = 0; dt < 4; ++dt) dst[dt * 16 + c] = oacc[dt][r] * inv;
    }
}

extern "C" void kernel_launch(void* const* d_in, const int* in_sizes, int n_in,
                              void* d_out, int out_size, void* d_ws, size_t ws_size,
                              hipStream_t stream) {
    const float* Q = (const float*)d_in[0];
    const float* K = (const float*)d_in[1];
    const float* V = (const float*)d_in[2];
    const int*  VL = (const int*)d_in[3];
    float*      Op = (float*)d_out;

    const int NB = in_sizes[3];               // 32
    const int S  = in_sizes[0] / (NB * 64);   // 2048
    const int qtiles = S / 64;                // 32
    const int jtiles = S / 64;
    const size_t nelem = (size_t)NB * S * 64;
    const size_t bf_bytes = nelem * 2;        // 8.39 MB each

    if (ws_size >= 256 + 2 * bf_bytes && NB <= 64) {
        int* cnt = (int*)d_ws;
        ushort_t* Kb = (ushort_t*)((char*)d_ws + 256);
        ushort_t* Vt = (ushort_t*)((char*)d_ws + 256 + bf_bytes);
        prep_kv<<<dim3(NB * jtiles), dim3(256), 0, stream>>>(K, V, Kb, Vt, cnt, S, jtiles);
        attn_persist<<<dim3(768), dim3(256), 0, stream>>>(
            Q, Kb, Vt, VL, Op, cnt, NB, S, qtiles);
    } else {
        attn_mono<<<dim3(NB * qtiles), dim3(256), 0, stream>>>(Q, K, V, VL, Op, NB, S);
    }
}